// Round 15
// baseline (106.310 us; speedup 1.0000x reference)
//
#include <hip/hip_runtime.h>
#include <hip/hip_bf16.h>

typedef __attribute__((ext_vector_type(4))) float f32x4;
typedef __attribute__((ext_vector_type(8))) short bf16x8;
typedef __attribute__((ext_vector_type(4))) int i32x4;

#define SEQ 1024
#define HIDV 768
#define NH 12
#define HD 64
#define QBLK 64

static __device__ __forceinline__ unsigned short f2b(float f) {
  unsigned u = __builtin_bit_cast(unsigned, f);
  u = (u + 0x7fffu + ((u >> 16) & 1u)) >> 16;
  return (unsigned short)u;
}

static __device__ __forceinline__ void gl16(const unsigned short* g, unsigned short* l) {
  __builtin_amdgcn_global_load_lds(
      (const __attribute__((address_space(1))) unsigned int*)g,
      (__attribute__((address_space(3))) unsigned int*)l, 16, 0, 0);
}

// barrier that waits ONLY on LDS ops (keeps global stores/loads in flight)
static __device__ __forceinline__ void bar_lgkm() {
  asm volatile("s_waitcnt lgkmcnt(0)" ::: "memory");
  __builtin_amdgcn_sched_barrier(0);
  __builtin_amdgcn_s_barrier();
  __builtin_amdgcn_sched_barrier(0);
}
// counted barrier: keep newest N VMEM ops (prefetch gl16s) in flight
#define BAR_VM(N)                                                         \
  do {                                                                    \
    asm volatile("s_waitcnt vmcnt(" #N ") lgkmcnt(0)" ::: "memory");      \
    __builtin_amdgcn_sched_barrier(0);                                    \
    __builtin_amdgcn_s_barrier();                                         \
    __builtin_amdgcn_sched_barrier(0);                                    \
  } while (0)

// ---------- convert f32 inputs -> bf16 (X, Wq, Wk, Wv, Wo contiguous in ws) ----------
__global__ __launch_bounds__(256) void convert_all(
    const float* __restrict__ X, const float* __restrict__ Wq,
    const float* __restrict__ Wk, const float* __restrict__ Wv,
    const float* __restrict__ Wo, unsigned short* __restrict__ dst) {
  long i = (long)blockIdx.x * 256 + threadIdx.x;
  const long N4 = (3145728L + 4 * 589824L) / 4;
  if (i >= N4) return;
  long e = i * 4;
  const float* src; long off;
  if (e < 3145728L)      { src = X;  off = e; }
  else if (e < 3735552L) { src = Wq; off = e - 3145728L; }
  else if (e < 4325376L) { src = Wk; off = e - 3735552L; }
  else if (e < 4915200L) { src = Wv; off = e - 4325376L; }
  else                   { src = Wo; off = e - 4915200L; }
  const float4 v = *reinterpret_cast<const float4*>(src + off);
  ushort4 o;
  o.x = f2b(v.x); o.y = f2b(v.y); o.z = f2b(v.z); o.w = f2b(v.w);
  *reinterpret_cast<ushort4*>(dst + e) = o;
}

// ---------- fused QKV GEMM: 3-buf LDS + counted-vmcnt barriers, vectorized epilogue ----------
__global__ __launch_bounds__(256) void qkv_gemm(
    const unsigned short* __restrict__ Xb,
    const unsigned short* __restrict__ Wqb, const unsigned short* __restrict__ Wkb,
    const unsigned short* __restrict__ Wvb,
    const float* __restrict__ bq, const float* __restrict__ bk, const float* __restrict__ bv,
    unsigned short* __restrict__ Qh, unsigned short* __restrict__ Kh,
    unsigned short* __restrict__ VT) {
  // 49152 B: la 3x4096, lb 3x4096 ushorts; Q/K epilogue reuses [0,17408) as [128][136]
  __shared__ __align__(16) unsigned short smem[24576];
#define LA(buf) (smem + (buf) * 4096)
#define LB(buf) (smem + 12288 + (buf) * 4096)
  const int z = blockIdx.z;
  const unsigned short* Wb = (z == 0) ? Wqb : (z == 1) ? Wkb : Wvb;
  const float* bias = (z == 0) ? bq : (z == 1) ? bk : bv;
  const int m0 = blockIdx.x * 128, n0 = blockIdx.y * 128;
  const int tid = threadIdx.x;
  const int wave = tid >> 6, lane = tid & 63, g = lane >> 4, c = lane & 15;
  const int wr = (wave >> 1) * 64, wc = (wave & 1) * 64;

  const int sr = wave * 16 + (lane >> 2);
  const int scol = (lane & 3) * 8;
  const unsigned short* Ag = &Xb[(size_t)(m0 + sr) * HIDV + scol];
  const unsigned short* Bg = &Wb[(size_t)(n0 + sr) * HIDV + scol];

#define QKV_STAGE(buf, kt)                                              \
  do {                                                                  \
    gl16(Ag + (kt), LA(buf) + (wave * 16) * 32);                        \
    gl16(Ag + (size_t)64 * HIDV + (kt), LA(buf) + (64 + wave * 16) * 32); \
    gl16(Bg + (kt), LB(buf) + (wave * 16) * 32);                        \
    gl16(Bg + (size_t)64 * HIDV + (kt), LB(buf) + (64 + wave * 16) * 32); \
  } while (0)

  QKV_STAGE(0, 0);
  QKV_STAGE(1, 32);
  BAR_VM(4);  // buf0 landed; buf1's 4 loads in flight

  f32x4 acc[4][4] = {};
#pragma unroll 3
  for (int t = 0; t < 24; t++) {
    const int cur = t % 3;
    if (t < 22) QKV_STAGE((t + 2) % 3, (t + 2) * 32);
    bf16x8 af[4], bfr[4];
#pragma unroll
    for (int m = 0; m < 4; m++)
      af[m] = *reinterpret_cast<bf16x8*>(LA(cur) + (wr + m * 16 + c) * 32 + g * 8);
#pragma unroll
    for (int n = 0; n < 4; n++)
      bfr[n] = *reinterpret_cast<bf16x8*>(LB(cur) + (wc + n * 16 + c) * 32 + g * 8);
#pragma unroll
    for (int m = 0; m < 4; m++)
#pragma unroll
      for (int n = 0; n < 4; n++)
        acc[m][n] = __builtin_amdgcn_mfma_f32_16x16x32_bf16(af[m], bfr[n], acc[m][n], 0, 0, 0);
    if (t < 22)      BAR_VM(4);  // buf[t+1] complete; buf[t+2] stays in flight
    else if (t < 23) BAR_VM(0);  // last buffer fully landed
  }
#undef QKV_STAGE
  float bv4[4];
#pragma unroll
  for (int n = 0; n < 4; n++) bv4[n] = bias[n0 + wc + n * 16 + c];
  if (z < 2) {
    __syncthreads();  // all waves done reading staging LDS before reuse
    // bounce acc through LDS [128][136] -> 16B coalesced head-split stores
#pragma unroll
    for (int m = 0; m < 4; m++)
#pragma unroll
      for (int n = 0; n < 4; n++)
#pragma unroll
        for (int r = 0; r < 4; r++)
          smem[(wr + m * 16 + g * 4 + r) * 136 + wc + n * 16 + c] =
              f2b(acc[m][n][r] + bv4[n]);
    __syncthreads();
    {
      const int hh = tid >> 7, row = tid & 127;
      const int grow = m0 + row;
      const int b_ = grow >> 10, s_ = grow & 1023;
      const int hgl = (n0 >> 6) + hh;
      unsigned short* dst =
          ((z == 0) ? Qh : Kh) + ((size_t)(b_ * NH + hgl) * SEQ + s_) * HD;
      const unsigned short* src = &smem[row * 136 + hh * 64];
#pragma unroll
      for (int j = 0; j < 8; j++)
        *reinterpret_cast<i32x4*>(&dst[j * 8]) =
            *reinterpret_cast<const i32x4*>(&src[j * 8]);
    }
  } else {
#pragma unroll
    for (int m = 0; m < 4; m++) {
      int rb_ = m0 + wr + m * 16 + g * 4;
      int b = rb_ >> 10, s = rb_ & 1023;
#pragma unroll
      for (int n = 0; n < 4; n++) {
        int col = n0 + wc + n * 16 + c;
        int h = col >> 6, d = col & 63;
        ushort4 o;
        o.x = f2b(acc[m][n][0] + bv4[n]);
        o.y = f2b(acc[m][n][1] + bv4[n]);
        o.z = f2b(acc[m][n][2] + bv4[n]);
        o.w = f2b(acc[m][n][3] + bv4[n]);
        *reinterpret_cast<ushort4*>(&VT[((size_t)(b * NH + h) * HD + d) * SEQ + s]) = o;
      }
    }
  }
#undef LA
#undef LB
}

// ---------- fused attention: r9/r10 version (best measured) ----------
#define EXPC 0.18033688f /* 0.125 * log2(e) */
__global__ __launch_bounds__(256) void attn_fused(
    const unsigned short* __restrict__ Qh, const unsigned short* __restrict__ Kh,
    const unsigned short* __restrict__ VT,
    float* __restrict__ probs, unsigned short* __restrict__ CTX) {
  __shared__ __align__(16) unsigned short ldsk[2][64 * 72];
  __shared__ __align__(16) unsigned short ldsv[2][64 * 72];
  __shared__ __align__(16) unsigned short lp[64 * 72];
  const int lin = blockIdx.x;
  const int swz = (lin & 7) * 96 + (lin >> 3);
  const int bh = swz >> 4, rb = (swz & 15) * QBLK;
  const int b = bh / NH, h = bh - b * NH;
  const unsigned short* Qp = Qh + (size_t)bh * SEQ * HD;
  const unsigned short* Kp = Kh + (size_t)bh * SEQ * HD;
  const unsigned short* Vp = VT + (size_t)bh * HD * SEQ;
  float* P = probs + (size_t)bh * SEQ * SEQ;
  const int tid = threadIdx.x, wave = tid >> 6, lane = tid & 63, g = lane >> 4, c = lane & 15;
  const int wrow = wave * 16;
  const int str = tid >> 3;
  const int stc = (tid & 7) * 8;

  bf16x8 aq[2];
#pragma unroll
  for (int ks = 0; ks < 2; ks++)
    aq[ks] = *reinterpret_cast<const bf16x8*>(&Qp[(size_t)(rb + wrow + c) * HD + ks * 32 + g * 8]);

  i32x4 kr0, kr1, vr0, vr1;
  kr0 = *reinterpret_cast<const i32x4*>(&Kp[(size_t)str * HD + stc]);
  kr1 = *reinterpret_cast<const i32x4*>(&Kp[(size_t)(str + 32) * HD + stc]);
  *reinterpret_cast<i32x4*>(&ldsk[0][str * 72 + stc]) = kr0;
  *reinterpret_cast<i32x4*>(&ldsk[0][(str + 32) * 72 + stc]) = kr1;
  bar_lgkm();

  // ---- sweep 1: row sums (1 barrier/tile) ----
  float lsum = 0.f;
  for (int ct = 0; ct < 16; ct++) {
    const int cur = ct & 1;
    if (ct < 15) {
      kr0 = *reinterpret_cast<const i32x4*>(&Kp[(size_t)((ct + 1) * 64 + str) * HD + stc]);
      kr1 = *reinterpret_cast<const i32x4*>(&Kp[(size_t)((ct + 1) * 64 + str + 32) * HD + stc]);
    }
    f32x4 sreg[4] = {};
    __builtin_amdgcn_s_setprio(1);
#pragma unroll
    for (int ks = 0; ks < 2; ks++) {
      bf16x8 kf[4];
#pragma unroll
      for (int kb = 0; kb < 4; kb++)
        kf[kb] = *reinterpret_cast<bf16x8*>(&ldsk[cur][(kb * 16 + c) * 72 + ks * 32 + g * 8]);
#pragma unroll
      for (int kb = 0; kb < 4; kb++)
        sreg[kb] = __builtin_amdgcn_mfma_f32_16x16x32_bf16(kf[kb], aq[ks], sreg[kb], 0, 0, 0);
    }
    __builtin_amdgcn_s_setprio(0);
#pragma unroll
    for (int kb = 0; kb < 4; kb++)
#pragma unroll
      for (int r = 0; r < 4; r++)
        lsum += __builtin_amdgcn_exp2f(sreg[kb][r] * EXPC);
    if (ct < 15) {
      *reinterpret_cast<i32x4*>(&ldsk[cur ^ 1][str * 72 + stc]) = kr0;
      *reinterpret_cast<i32x4*>(&ldsk[cur ^ 1][(str + 32) * 72 + stc]) = kr1;
      bar_lgkm();
    }
  }
  float s = lsum;
  s += __shfl_xor(s, 16);
  s += __shfl_xor(s, 32);
  const float linv = 1.f / s;

  // ---- sweep 2 prologue: stage K0 + V0 ----
  kr0 = *reinterpret_cast<const i32x4*>(&Kp[(size_t)str * HD + stc]);
  kr1 = *reinterpret_cast<const i32x4*>(&Kp[(size_t)(str + 32) * HD + stc]);
  vr0 = *reinterpret_cast<const i32x4*>(&Vp[(size_t)str * SEQ + stc]);
  vr1 = *reinterpret_cast<const i32x4*>(&Vp[(size_t)(str + 32) * SEQ + stc]);
  *reinterpret_cast<i32x4*>(&ldsk[0][str * 72 + stc]) = kr0;
  *reinterpret_cast<i32x4*>(&ldsk[0][(str + 32) * 72 + stc]) = kr1;
  *reinterpret_cast<i32x4*>(&ldsv[0][str * 72 + stc]) = vr0;
  *reinterpret_cast<i32x4*>(&ldsv[0][(str + 32) * 72 + stc]) = vr1;
  bar_lgkm();

  // ---- sweep 2: QKT -> probs -> PV -> stage-next -> ONE barrier ----
  f32x4 acc[4] = {};
  for (int ct = 0; ct < 16; ct++) {
    const int cur = ct & 1;
    if (ct < 15) {
      kr0 = *reinterpret_cast<const i32x4*>(&Kp[(size_t)((ct + 1) * 64 + str) * HD + stc]);
      kr1 = *reinterpret_cast<const i32x4*>(&Kp[(size_t)((ct + 1) * 64 + str + 32) * HD + stc]);
      vr0 = *reinterpret_cast<const i32x4*>(&Vp[(size_t)str * SEQ + (ct + 1) * 64 + stc]);
      vr1 = *reinterpret_cast<const i32x4*>(&Vp[(size_t)(str + 32) * SEQ + (ct + 1) * 64 + stc]);
    }
    f32x4 sreg[4] = {};
    __builtin_amdgcn_s_setprio(1);
#pragma unroll
    for (int ks = 0; ks < 2; ks++) {
      bf16x8 kf[4];
#pragma unroll
      for (int kb = 0; kb < 4; kb++)
        kf[kb] = *reinterpret_cast<bf16x8*>(&ldsk[cur][(kb * 16 + c) * 72 + ks * 32 + g * 8]);
#pragma unroll
      for (int kb = 0; kb < 4; kb++)
        sreg[kb] = __builtin_amdgcn_mfma_f32_16x16x32_bf16(kf[kb], aq[ks], sreg[kb], 0, 0, 0);
    }
    __builtin_amdgcn_s_setprio(0);
    {
      float* Prow = &P[(size_t)(rb + wrow + c) * SEQ + ct * 64];
#pragma unroll
      for (int kb = 0; kb < 4; kb++) {
        f32x4 p;
#pragma unroll
        for (int r = 0; r < 4; r++)
          p[r] = __builtin_amdgcn_exp2f(sreg[kb][r] * EXPC) * linv;
        *reinterpret_cast<f32x4*>(&Prow[kb * 16 + g * 4]) = p;
        uint2 pk;
        pk.x = (unsigned)f2b(p[0]) | ((unsigned)f2b(p[1]) << 16);
        pk.y = (unsigned)f2b(p[2]) | ((unsigned)f2b(p[3]) << 16);
        *reinterpret_cast<uint2*>(&lp[(wrow + c) * 72 + kb * 16 + g * 4]) = pk;
      }
    }
    __builtin_amdgcn_s_setprio(1);
#pragma unroll
    for (int ks = 0; ks < 2; ks++) {
      bf16x8 pa, vf[4];
      pa = *reinterpret_cast<bf16x8*>(&lp[(wrow + c) * 72 + ks * 32 + g * 8]);
#pragma unroll
      for (int db = 0; db < 4; db++)
        vf[db] = *reinterpret_cast<bf16x8*>(&ldsv[cur][(db * 16 + c) * 72 + ks * 32 + g * 8]);
#pragma unroll
      for (int db = 0; db < 4; db++)
        acc[db] = __builtin_amdgcn_mfma_f32_16x16x32_bf16(pa, vf[db], acc[db], 0, 0, 0);
    }
    __builtin_amdgcn_s_setprio(0);
    if (ct < 15) {
      *reinterpret_cast<i32x4*>(&ldsk[cur ^ 1][str * 72 + stc]) = kr0;
      *reinterpret_cast<i32x4*>(&ldsk[cur ^ 1][(str + 32) * 72 + stc]) = kr1;
      *reinterpret_cast<i32x4*>(&ldsv[cur ^ 1][str * 72 + stc]) = vr0;
      *reinterpret_cast<i32x4*>(&ldsv[cur ^ 1][(str + 32) * 72 + stc]) = vr1;
      bar_lgkm();
    }
  }

  // ---- CTX epilogue ----
  bar_lgkm();
#pragma unroll
  for (int db = 0; db < 4; db++)
#pragma unroll
    for (int r = 0; r < 4; r++)
      lp[(wrow + g * 4 + r) * 72 + db * 16 + c] = f2b(acc[db][r]);
  bar_lgkm();
  {
    const int q = tid >> 2, seg = (tid & 3) * 16;
    const unsigned short* src = &lp[q * 72 + seg];
    unsigned short* dst = &CTX[(size_t)(b * SEQ + rb + q) * HIDV + h * HD + seg];
    i32x4 t0 = *reinterpret_cast<const i32x4*>(&src[0]);
    i32x4 t1 = *reinterpret_cast<const i32x4*>(&src[8]);
    *reinterpret_cast<i32x4*>(&dst[0]) = t0;
    *reinterpret_cast<i32x4*>(&dst[8]) = t1;
  }
}

// ---------- output projection: 64x128 tile (384 blocks), T3-min pipeline ----------
__global__ __launch_bounds__(256) void proj_gemm(
    const unsigned short* __restrict__ Ab, const unsigned short* __restrict__ Wb,
    const float* __restrict__ bias, float* __restrict__ out) {
  __shared__ __align__(16) unsigned short la[2][64 * 32];
  __shared__ __align__(16) unsigned short lb[2][128 * 32];
  const int m0 = blockIdx.x * 64, n0 = blockIdx.y * 128;
  const int tid = threadIdx.x;
  const int wave = tid >> 6, lane = tid & 63, g = lane >> 4, c = lane & 15;
  const int wr = (wave >> 1) * 32, wc = (wave & 1) * 64;
  const int srb = wave * 16 + (lane >> 2);
  const int scol = (lane & 3) * 8;
  const unsigned short* Ag = &Ab[(size_t)(m0 + srb) * HIDV + scol];
  const unsigned short* Bg = &Wb[(size_t)(n0 + srb) * HIDV + scol];

#define PROJ_STAGE(buf, kt)                                               \
  do {                                                                    \
    gl16(Ag + (kt), &la[buf][(wave * 16) * 32]);                          \
    gl16(Bg + (kt), &lb[buf][(wave * 16) * 32]);                          \
    gl16(Bg + (size_t)64 * HIDV + (kt), &lb[buf][(64 + wave * 16) * 32]); \
  } while (0)

  PROJ_STAGE(0, 0);
  __syncthreads();

  f32x4 acc[2][4] = {};
  for (int t = 0; t < 24; t++) {
    const int cur = t & 1;
    if (t < 23) PROJ_STAGE(cur ^ 1, (t + 1) * 32);
    bf16x8 af[2], bfr[4];
#pragma unroll
    for (int m = 0; m < 2; m++)
      af[m] = *reinterpret_cast<bf16x8*>(&la[cur][(wr + m * 16 + c) * 32 + g * 8]);
#pragma unroll
    for (int n = 0; n < 4; n++)
      bfr[n] = *reinterpret_cast<bf16x8*>(&lb[cur][(wc + n * 16 + c) * 32 + g * 8]);
#pragma unroll
    for (int m = 0; m < 2; m++)
#pragma unroll
      for (int n = 0; n < 4; n++)
        acc[m][n] = __builtin_amdgcn_mfma_f32_16x16x32_bf16(af[m], bfr[n], acc[m][n], 0, 0, 0);
    __syncthreads();
  }
#undef PROJ_STAGE
  float bv4[4];
#pragma unroll
  for (int n = 0; n < 4; n++) bv4[n] = bias[n0 + wc + n * 16 + c];
#pragma unroll
  for (int m = 0; m < 2; m++) {
    int rb_ = m0 + wr + m * 16 + g * 4;
#pragma unroll
    for (int n = 0; n < 4; n++) {
      int col = n0 + wc + n * 16 + c;
#pragma unroll
      for (int r = 0; r < 4; r++)
        out[(size_t)(rb_ + r) * HIDV + col] = acc[m][n][r] + bv4[n];
    }
  }
}

extern "C" void kernel_launch(void* const* d_in, const int* in_sizes, int n_in,
                              void* d_out, int out_size, void* d_ws, size_t ws_size,
                              hipStream_t stream) {
  const float* X  = (const float*)d_in[0];
  const float* Wq = (const float*)d_in[1];
  const float* bq = (const float*)d_in[2];
  const float* Wk = (const float*)d_in[3];
  const float* bk = (const float*)d_in[4];
  const float* Wv = (const float*)d_in[5];
  const float* bv = (const float*)d_in[6];
  const float* Wo = (const float*)d_in[7];
  const float* bo = (const float*)d_in[8];
  float* out = (float*)d_out;
  float* probs = out + 3145728;  // output 1 region

  unsigned short* Xb  = (unsigned short*)d_ws;        // [4096,768]
  unsigned short* Wqb = Xb + 3145728;                 // [768,768]
  unsigned short* Wkb = Wqb + 589824;
  unsigned short* Wvb = Wkb + 589824;
  unsigned short* Wob = Wvb + 589824;
  unsigned short* Qh  = Wob + 589824;                 // [4,12,1024,64]
  unsigned short* Kh  = Qh + 3145728;
  unsigned short* VT  = Kh + 3145728;                 // [4,12,64,1024]
  unsigned short* CTX = VT + 3145728;                 // [4096,768]

  convert_all<<<5376, 256, 0, stream>>>(X, Wq, Wk, Wv, Wo, Xb);
  qkv_gemm<<<dim3(32, 6, 3), 256, 0, stream>>>(Xb, Wqb, Wkb, Wvb, bq, bk, bv, Qh, Kh, VT);
  attn_fused<<<dim3(768), 256, 0, stream>>>(Qh, Kh, VT, probs, CTX);
  proj_gemm<<<dim3(64, 6), 256, 0, stream>>>(CTX, Wob, bo, out);
}

// Round 16
// 105.066 us; speedup vs baseline: 1.0118x; 1.0118x over previous
//
#include <hip/hip_runtime.h>
#include <hip/hip_bf16.h>

typedef __attribute__((ext_vector_type(4))) float f32x4;
typedef __attribute__((ext_vector_type(8))) short bf16x8;
typedef __attribute__((ext_vector_type(4))) int i32x4;

#define SEQ 1024
#define HIDV 768
#define NH 12
#define HD 64
#define QBLK 64

static __device__ __forceinline__ unsigned short f2b(float f) {
  unsigned u = __builtin_bit_cast(unsigned, f);
  u = (u + 0x7fffu + ((u >> 16) & 1u)) >> 16;
  return (unsigned short)u;
}

static __device__ __forceinline__ void gl16(const unsigned short* g, unsigned short* l) {
  __builtin_amdgcn_global_load_lds(
      (const __attribute__((address_space(1))) unsigned int*)g,
      (__attribute__((address_space(3))) unsigned int*)l, 16, 0, 0);
}

// barrier that waits ONLY on LDS ops (keeps global stores/loads in flight)
static __device__ __forceinline__ void bar_lgkm() {
  asm volatile("s_waitcnt lgkmcnt(0)" ::: "memory");
  __builtin_amdgcn_sched_barrier(0);
  __builtin_amdgcn_s_barrier();
  __builtin_amdgcn_sched_barrier(0);
}

// ---------- convert f32 inputs -> bf16 (X, Wq, Wk, Wv, Wo contiguous in ws) ----------
__global__ __launch_bounds__(256) void convert_all(
    const float* __restrict__ X, const float* __restrict__ Wq,
    const float* __restrict__ Wk, const float* __restrict__ Wv,
    const float* __restrict__ Wo, unsigned short* __restrict__ dst) {
  long i = (long)blockIdx.x * 256 + threadIdx.x;
  const long N4 = (3145728L + 4 * 589824L) / 4;
  if (i >= N4) return;
  long e = i * 4;
  const float* src; long off;
  if (e < 3145728L)      { src = X;  off = e; }
  else if (e < 3735552L) { src = Wq; off = e - 3145728L; }
  else if (e < 4325376L) { src = Wk; off = e - 3735552L; }
  else if (e < 4915200L) { src = Wv; off = e - 4325376L; }
  else                   { src = Wo; off = e - 4915200L; }
  const float4 v = *reinterpret_cast<const float4*>(src + off);
  ushort4 o;
  o.x = f2b(v.x); o.y = f2b(v.y); o.z = f2b(v.z); o.w = f2b(v.w);
  *reinterpret_cast<ushort4*>(dst + e) = o;
}

// ---------- fused QKV GEMM: T3-min pipeline + vectorized Q/K epilogue ----------
__global__ __launch_bounds__(256) void qkv_gemm(
    const unsigned short* __restrict__ Xb,
    const unsigned short* __restrict__ Wqb, const unsigned short* __restrict__ Wkb,
    const unsigned short* __restrict__ Wvb,
    const float* __restrict__ bq, const float* __restrict__ bk, const float* __restrict__ bv,
    unsigned short* __restrict__ Qh, unsigned short* __restrict__ Kh,
    unsigned short* __restrict__ VT) {
  // 34816 B: staging la=[0,8192) lb=[8192,16384) ushorts; epilogue reuses all as [128][136]
  __shared__ __align__(16) unsigned short smem[17408];
#define LA(buf) (smem + (buf) * 4096)
#define LB(buf) (smem + 8192 + (buf) * 4096)
  const int z = blockIdx.z;
  const unsigned short* Wb = (z == 0) ? Wqb : (z == 1) ? Wkb : Wvb;
  const float* bias = (z == 0) ? bq : (z == 1) ? bk : bv;
  const int m0 = blockIdx.x * 128, n0 = blockIdx.y * 128;
  const int tid = threadIdx.x;
  const int wave = tid >> 6, lane = tid & 63, g = lane >> 4, c = lane & 15;
  const int wr = (wave >> 1) * 64, wc = (wave & 1) * 64;

  const int sr = wave * 16 + (lane >> 2);
  const int scol = (lane & 3) * 8;
  const unsigned short* Ag = &Xb[(size_t)(m0 + sr) * HIDV + scol];
  const unsigned short* Bg = &Wb[(size_t)(n0 + sr) * HIDV + scol];

  gl16(Ag, LA(0) + (wave * 16) * 32);
  gl16(Ag + (size_t)64 * HIDV, LA(0) + (64 + wave * 16) * 32);
  gl16(Bg, LB(0) + (wave * 16) * 32);
  gl16(Bg + (size_t)64 * HIDV, LB(0) + (64 + wave * 16) * 32);
  __syncthreads();

  f32x4 acc[4][4] = {};
  for (int t = 0; t < 24; t++) {
    const int cur = t & 1;
    if (t < 23) {
      const int kt = (t + 1) * 32;
      gl16(Ag + kt, LA(cur ^ 1) + (wave * 16) * 32);
      gl16(Ag + (size_t)64 * HIDV + kt, LA(cur ^ 1) + (64 + wave * 16) * 32);
      gl16(Bg + kt, LB(cur ^ 1) + (wave * 16) * 32);
      gl16(Bg + (size_t)64 * HIDV + kt, LB(cur ^ 1) + (64 + wave * 16) * 32);
    }
    bf16x8 af[4], bfr[4];
#pragma unroll
    for (int m = 0; m < 4; m++)
      af[m] = *reinterpret_cast<bf16x8*>(LA(cur) + (wr + m * 16 + c) * 32 + g * 8);
#pragma unroll
    for (int n = 0; n < 4; n++)
      bfr[n] = *reinterpret_cast<bf16x8*>(LB(cur) + (wc + n * 16 + c) * 32 + g * 8);
#pragma unroll
    for (int m = 0; m < 4; m++)
#pragma unroll
      for (int n = 0; n < 4; n++)
        acc[m][n] = __builtin_amdgcn_mfma_f32_16x16x32_bf16(af[m], bfr[n], acc[m][n], 0, 0, 0);
    __syncthreads();
  }
  float bv4[4];
#pragma unroll
  for (int n = 0; n < 4; n++) bv4[n] = bias[n0 + wc + n * 16 + c];
  if (z < 2) {
    // bounce acc through LDS [128][136] -> 16B coalesced head-split stores
#pragma unroll
    for (int m = 0; m < 4; m++)
#pragma unroll
      for (int n = 0; n < 4; n++)
#pragma unroll
        for (int r = 0; r < 4; r++)
          smem[(wr + m * 16 + g * 4 + r) * 136 + wc + n * 16 + c] =
              f2b(acc[m][n][r] + bv4[n]);
    __syncthreads();
    {
      const int hh = tid >> 7, row = tid & 127;
      const int grow = m0 + row;
      const int b_ = grow >> 10, s_ = grow & 1023;
      const int hgl = (n0 >> 6) + hh;
      unsigned short* dst =
          ((z == 0) ? Qh : Kh) + ((size_t)(b_ * NH + hgl) * SEQ + s_) * HD;
      const unsigned short* src = &smem[row * 136 + hh * 64];
#pragma unroll
      for (int j = 0; j < 8; j++)
        *reinterpret_cast<i32x4*>(&dst[j * 8]) =
            *reinterpret_cast<const i32x4*>(&src[j * 8]);
    }
  } else {
#pragma unroll
    for (int m = 0; m < 4; m++) {
      int rb_ = m0 + wr + m * 16 + g * 4;
      int b = rb_ >> 10, s = rb_ & 1023;
#pragma unroll
      for (int n = 0; n < 4; n++) {
        int col = n0 + wc + n * 16 + c;
        int h = col >> 6, d = col & 63;
        ushort4 o;
        o.x = f2b(acc[m][n][0] + bv4[n]);
        o.y = f2b(acc[m][n][1] + bv4[n]);
        o.z = f2b(acc[m][n][2] + bv4[n]);
        o.w = f2b(acc[m][n][3] + bv4[n]);
        *reinterpret_cast<ushort4*>(&VT[((size_t)(b * NH + h) * HD + d) * SEQ + s]) = o;
      }
    }
  }
#undef LA
#undef LB
}

// ---------- fused attention: r9/r10 version (best measured) ----------
#define EXPC 0.18033688f /* 0.125 * log2(e) */
__global__ __launch_bounds__(256) void attn_fused(
    const unsigned short* __restrict__ Qh, const unsigned short* __restrict__ Kh,
    const unsigned short* __restrict__ VT,
    float* __restrict__ probs, unsigned short* __restrict__ CTX) {
  __shared__ __align__(16) unsigned short ldsk[2][64 * 72];
  __shared__ __align__(16) unsigned short ldsv[2][64 * 72];
  __shared__ __align__(16) unsigned short lp[64 * 72];
  const int lin = blockIdx.x;
  const int swz = (lin & 7) * 96 + (lin >> 3);
  const int bh = swz >> 4, rb = (swz & 15) * QBLK;
  const int b = bh / NH, h = bh - b * NH;
  const unsigned short* Qp = Qh + (size_t)bh * SEQ * HD;
  const unsigned short* Kp = Kh + (size_t)bh * SEQ * HD;
  const unsigned short* Vp = VT + (size_t)bh * HD * SEQ;
  float* P = probs + (size_t)bh * SEQ * SEQ;
  const int tid = threadIdx.x, wave = tid >> 6, lane = tid & 63, g = lane >> 4, c = lane & 15;
  const int wrow = wave * 16;
  const int str = tid >> 3;
  const int stc = (tid & 7) * 8;

  bf16x8 aq[2];
#pragma unroll
  for (int ks = 0; ks < 2; ks++)
    aq[ks] = *reinterpret_cast<const bf16x8*>(&Qp[(size_t)(rb + wrow + c) * HD + ks * 32 + g * 8]);

  i32x4 kr0, kr1, vr0, vr1;
  kr0 = *reinterpret_cast<const i32x4*>(&Kp[(size_t)str * HD + stc]);
  kr1 = *reinterpret_cast<const i32x4*>(&Kp[(size_t)(str + 32) * HD + stc]);
  *reinterpret_cast<i32x4*>(&ldsk[0][str * 72 + stc]) = kr0;
  *reinterpret_cast<i32x4*>(&ldsk[0][(str + 32) * 72 + stc]) = kr1;
  bar_lgkm();

  // ---- sweep 1: row sums (1 barrier/tile) ----
  float lsum = 0.f;
  for (int ct = 0; ct < 16; ct++) {
    const int cur = ct & 1;
    if (ct < 15) {
      kr0 = *reinterpret_cast<const i32x4*>(&Kp[(size_t)((ct + 1) * 64 + str) * HD + stc]);
      kr1 = *reinterpret_cast<const i32x4*>(&Kp[(size_t)((ct + 1) * 64 + str + 32) * HD + stc]);
    }
    f32x4 sreg[4] = {};
    __builtin_amdgcn_s_setprio(1);
#pragma unroll
    for (int ks = 0; ks < 2; ks++) {
      bf16x8 kf[4];
#pragma unroll
      for (int kb = 0; kb < 4; kb++)
        kf[kb] = *reinterpret_cast<bf16x8*>(&ldsk[cur][(kb * 16 + c) * 72 + ks * 32 + g * 8]);
#pragma unroll
      for (int kb = 0; kb < 4; kb++)
        sreg[kb] = __builtin_amdgcn_mfma_f32_16x16x32_bf16(kf[kb], aq[ks], sreg[kb], 0, 0, 0);
    }
    __builtin_amdgcn_s_setprio(0);
#pragma unroll
    for (int kb = 0; kb < 4; kb++)
#pragma unroll
      for (int r = 0; r < 4; r++)
        lsum += __builtin_amdgcn_exp2f(sreg[kb][r] * EXPC);
    if (ct < 15) {
      *reinterpret_cast<i32x4*>(&ldsk[cur ^ 1][str * 72 + stc]) = kr0;
      *reinterpret_cast<i32x4*>(&ldsk[cur ^ 1][(str + 32) * 72 + stc]) = kr1;
      bar_lgkm();
    }
  }
  float s = lsum;
  s += __shfl_xor(s, 16);
  s += __shfl_xor(s, 32);
  const float linv = 1.f / s;

  // ---- sweep 2 prologue: stage K0 + V0 ----
  kr0 = *reinterpret_cast<const i32x4*>(&Kp[(size_t)str * HD + stc]);
  kr1 = *reinterpret_cast<const i32x4*>(&Kp[(size_t)(str + 32) * HD + stc]);
  vr0 = *reinterpret_cast<const i32x4*>(&Vp[(size_t)str * SEQ + stc]);
  vr1 = *reinterpret_cast<const i32x4*>(&Vp[(size_t)(str + 32) * SEQ + stc]);
  *reinterpret_cast<i32x4*>(&ldsk[0][str * 72 + stc]) = kr0;
  *reinterpret_cast<i32x4*>(&ldsk[0][(str + 32) * 72 + stc]) = kr1;
  *reinterpret_cast<i32x4*>(&ldsv[0][str * 72 + stc]) = vr0;
  *reinterpret_cast<i32x4*>(&ldsv[0][(str + 32) * 72 + stc]) = vr1;
  bar_lgkm();

  // ---- sweep 2: QKT -> probs -> PV -> stage-next -> ONE barrier ----
  f32x4 acc[4] = {};
  for (int ct = 0; ct < 16; ct++) {
    const int cur = ct & 1;
    if (ct < 15) {
      kr0 = *reinterpret_cast<const i32x4*>(&Kp[(size_t)((ct + 1) * 64 + str) * HD + stc]);
      kr1 = *reinterpret_cast<const i32x4*>(&Kp[(size_t)((ct + 1) * 64 + str + 32) * HD + stc]);
      vr0 = *reinterpret_cast<const i32x4*>(&Vp[(size_t)str * SEQ + (ct + 1) * 64 + stc]);
      vr1 = *reinterpret_cast<const i32x4*>(&Vp[(size_t)(str + 32) * SEQ + (ct + 1) * 64 + stc]);
    }
    f32x4 sreg[4] = {};
    __builtin_amdgcn_s_setprio(1);
#pragma unroll
    for (int ks = 0; ks < 2; ks++) {
      bf16x8 kf[4];
#pragma unroll
      for (int kb = 0; kb < 4; kb++)
        kf[kb] = *reinterpret_cast<bf16x8*>(&ldsk[cur][(kb * 16 + c) * 72 + ks * 32 + g * 8]);
#pragma unroll
      for (int kb = 0; kb < 4; kb++)
        sreg[kb] = __builtin_amdgcn_mfma_f32_16x16x32_bf16(kf[kb], aq[ks], sreg[kb], 0, 0, 0);
    }
    __builtin_amdgcn_s_setprio(0);
    {
      float* Prow = &P[(size_t)(rb + wrow + c) * SEQ + ct * 64];
#pragma unroll
      for (int kb = 0; kb < 4; kb++) {
        f32x4 p;
#pragma unroll
        for (int r = 0; r < 4; r++)
          p[r] = __builtin_amdgcn_exp2f(sreg[kb][r] * EXPC) * linv;
        *reinterpret_cast<f32x4*>(&Prow[kb * 16 + g * 4]) = p;
        uint2 pk;
        pk.x = (unsigned)f2b(p[0]) | ((unsigned)f2b(p[1]) << 16);
        pk.y = (unsigned)f2b(p[2]) | ((unsigned)f2b(p[3]) << 16);
        *reinterpret_cast<uint2*>(&lp[(wrow + c) * 72 + kb * 16 + g * 4]) = pk;
      }
    }
    __builtin_amdgcn_s_setprio(1);
#pragma unroll
    for (int ks = 0; ks < 2; ks++) {
      bf16x8 pa, vf[4];
      pa = *reinterpret_cast<bf16x8*>(&lp[(wrow + c) * 72 + ks * 32 + g * 8]);
#pragma unroll
      for (int db = 0; db < 4; db++)
        vf[db] = *reinterpret_cast<bf16x8*>(&ldsv[cur][(db * 16 + c) * 72 + ks * 32 + g * 8]);
#pragma unroll
      for (int db = 0; db < 4; db++)
        acc[db] = __builtin_amdgcn_mfma_f32_16x16x32_bf16(pa, vf[db], acc[db], 0, 0, 0);
    }
    __builtin_amdgcn_s_setprio(0);
    if (ct < 15) {
      *reinterpret_cast<i32x4*>(&ldsk[cur ^ 1][str * 72 + stc]) = kr0;
      *reinterpret_cast<i32x4*>(&ldsk[cur ^ 1][(str + 32) * 72 + stc]) = kr1;
      *reinterpret_cast<i32x4*>(&ldsv[cur ^ 1][str * 72 + stc]) = vr0;
      *reinterpret_cast<i32x4*>(&ldsv[cur ^ 1][(str + 32) * 72 + stc]) = vr1;
      bar_lgkm();
    }
  }

  // ---- CTX epilogue ----
  bar_lgkm();
#pragma unroll
  for (int db = 0; db < 4; db++)
#pragma unroll
    for (int r = 0; r < 4; r++)
      lp[(wrow + g * 4 + r) * 72 + db * 16 + c] = f2b(acc[db][r]);
  bar_lgkm();
  {
    const int q = tid >> 2, seg = (tid & 3) * 16;
    const unsigned short* src = &lp[q * 72 + seg];
    unsigned short* dst = &CTX[(size_t)(b * SEQ + rb + q) * HIDV + h * HD + seg];
    i32x4 t0 = *reinterpret_cast<const i32x4*>(&src[0]);
    i32x4 t1 = *reinterpret_cast<const i32x4*>(&src[8]);
    *reinterpret_cast<i32x4*>(&dst[0]) = t0;
    *reinterpret_cast<i32x4*>(&dst[8]) = t1;
  }
}

// ---------- output projection: 64x128 tile (384 blocks), T3-min pipeline ----------
__global__ __launch_bounds__(256) void proj_gemm(
    const unsigned short* __restrict__ Ab, const unsigned short* __restrict__ Wb,
    const float* __restrict__ bias, float* __restrict__ out) {
  __shared__ __align__(16) unsigned short la[2][64 * 32];
  __shared__ __align__(16) unsigned short lb[2][128 * 32];
  const int m0 = blockIdx.x * 64, n0 = blockIdx.y * 128;
  const int tid = threadIdx.x;
  const int wave = tid >> 6, lane = tid & 63, g = lane >> 4, c = lane & 15;
  const int wr = (wave >> 1) * 32, wc = (wave & 1) * 64;
  const int srb = wave * 16 + (lane >> 2);
  const int scol = (lane & 3) * 8;
  const unsigned short* Ag = &Ab[(size_t)(m0 + srb) * HIDV + scol];
  const unsigned short* Bg = &Wb[(size_t)(n0 + srb) * HIDV + scol];

#define PROJ_STAGE(buf, kt)                                               \
  do {                                                                    \
    gl16(Ag + (kt), &la[buf][(wave * 16) * 32]);                          \
    gl16(Bg + (kt), &lb[buf][(wave * 16) * 32]);                          \
    gl16(Bg + (size_t)64 * HIDV + (kt), &lb[buf][(64 + wave * 16) * 32]); \
  } while (0)

  PROJ_STAGE(0, 0);
  __syncthreads();

  f32x4 acc[2][4] = {};
  for (int t = 0; t < 24; t++) {
    const int cur = t & 1;
    if (t < 23) PROJ_STAGE(cur ^ 1, (t + 1) * 32);
    bf16x8 af[2], bfr[4];
#pragma unroll
    for (int m = 0; m < 2; m++)
      af[m] = *reinterpret_cast<bf16x8*>(&la[cur][(wr + m * 16 + c) * 32 + g * 8]);
#pragma unroll
    for (int n = 0; n < 4; n++)
      bfr[n] = *reinterpret_cast<bf16x8*>(&lb[cur][(wc + n * 16 + c) * 32 + g * 8]);
#pragma unroll
    for (int m = 0; m < 2; m++)
#pragma unroll
      for (int n = 0; n < 4; n++)
        acc[m][n] = __builtin_amdgcn_mfma_f32_16x16x32_bf16(af[m], bfr[n], acc[m][n], 0, 0, 0);
    __syncthreads();
  }
#undef PROJ_STAGE
  float bv4[4];
#pragma unroll
  for (int n = 0; n < 4; n++) bv4[n] = bias[n0 + wc + n * 16 + c];
#pragma unroll
  for (int m = 0; m < 2; m++) {
    int rb_ = m0 + wr + m * 16 + g * 4;
#pragma unroll
    for (int n = 0; n < 4; n++) {
      int col = n0 + wc + n * 16 + c;
#pragma unroll
      for (int r = 0; r < 4; r++)
        out[(size_t)(rb_ + r) * HIDV + col] = acc[m][n][r] + bv4[n];
    }
  }
}

extern "C" void kernel_launch(void* const* d_in, const int* in_sizes, int n_in,
                              void* d_out, int out_size, void* d_ws, size_t ws_size,
                              hipStream_t stream) {
  const float* X  = (const float*)d_in[0];
  const float* Wq = (const float*)d_in[1];
  const float* bq = (const float*)d_in[2];
  const float* Wk = (const float*)d_in[3];
  const float* bk = (const float*)d_in[4];
  const float* Wv = (const float*)d_in[5];
  const float* bv = (const float*)d_in[6];
  const float* Wo = (const float*)d_in[7];
  const float* bo = (const float*)d_in[8];
  float* out = (float*)d_out;
  float* probs = out + 3145728;  // output 1 region

  unsigned short* Xb  = (unsigned short*)d_ws;        // [4096,768]
  unsigned short* Wqb = Xb + 3145728;                 // [768,768]
  unsigned short* Wkb = Wqb + 589824;
  unsigned short* Wvb = Wkb + 589824;
  unsigned short* Wob = Wvb + 589824;
  unsigned short* Qh  = Wob + 589824;                 // [4,12,1024,64]
  unsigned short* Kh  = Qh + 3145728;
  unsigned short* VT  = Kh + 3145728;                 // [4,12,64,1024]
  unsigned short* CTX = VT + 3145728;                 // [4096,768]

  convert_all<<<5376, 256, 0, stream>>>(X, Wq, Wk, Wv, Wo, Xb);
  qkv_gemm<<<dim3(32, 6, 3), 256, 0, stream>>>(Xb, Wqb, Wkb, Wvb, bq, bk, bv, Qh, Kh, VT);
  attn_fused<<<dim3(768), 256, 0, stream>>>(Qh, Kh, VT, probs, CTX);
  proj_gemm<<<dim3(64, 6), 256, 0, stream>>>(CTX, Wob, bo, out);
}